// Round 6
// baseline (67.349 us; speedup 1.0000x reference)
//
#include <hip/hip_runtime.h>
#include <math.h>

#define B_ 4
#define T_ 256
#define U_ 48
#define H_ 512
#define V_ 1024
#define BLANK_ (V_-1)

#define GM 1220        // B*T + B*(U+1)
#define GM_ENC 1024    // B*T
#define APAD 1280

#define NEGINF (-__builtin_inff())
#define INVLN2 1.4426950408889634f
#define LN2F   0.6931471805599453f

typedef __attribute__((ext_vector_type(8))) short short8;
typedef __attribute__((ext_vector_type(4))) float f32x4;

__device__ __forceinline__ unsigned short f2bf(float x) {
    union { float f; unsigned int u; } c; c.f = x;
    unsigned int r = c.u + 0x7FFF + ((c.u >> 16) & 1);   // RNE
    return (unsigned short)(r >> 16);
}
__device__ __forceinline__ float bf2f(unsigned short u) {
    union { unsigned int i; float f; } c; c.i = ((unsigned int)u) << 16; return c.f;
}
__device__ __forceinline__ unsigned int cvt_pk_bf16(float lo, float hi) {
    unsigned int r;
    asm("v_cvt_pk_bf16_f32 %0, %1, %2" : "=v"(r) : "v"(lo), "v"(hi));
    return r;
}
// wave-wide shift-right-by-1 via DPP (pure VALU; lane0 <- fill)
__device__ __forceinline__ float wave_shr1(float x, float fill) {
    int r = __builtin_amdgcn_update_dpp(__builtin_bit_cast(int, fill),
                                        __builtin_bit_cast(int, x),
                                        0x138 /*wave_shr:1*/, 0xf, 0xf, false);
    return __builtin_bit_cast(float, r);
}
// logaddexp in log2 domain
__device__ __forceinline__ float lad2(float x, float y) {
    float mx = fmaxf(x, y);
    float mn = fminf(x, y);
    return mx + __builtin_amdgcn_logf(1.0f + __builtin_amdgcn_exp2f(mn - mx));
}

// ---------------- K1: Pexp = exp2(([enc;dec]@W^T + bias)·log2e) bf16
// 128x128 tile, 512 threads, 8 waves (2M x 4N), wave tile 64x32, reg-prefetch.
__global__ __launch_bounds__(512) void gemm1_kernel(
    const float* __restrict__ enc, const float* __restrict__ dec,
    const float* __restrict__ W, const float* __restrict__ bias,
    unsigned short* __restrict__ Pexp)
{
    __shared__ __attribute__((aligned(16))) unsigned short As[128 * 64];
    __shared__ __attribute__((aligned(16))) unsigned short Bs[128 * 64];
    const int tid  = threadIdx.x;
    const int lane = tid & 63, wave = tid >> 6;
    const int wm = wave >> 2, wn = wave & 3;        // 2 x 4 wave grid
    const int row0 = blockIdx.y * 128, col0 = blockIdx.x * 128;
    const int srow = tid >> 2;          // staging row 0..127
    const int scg  = (tid & 3) * 16;    // fp32 col group

    f32x4 acc[4][2];
    #pragma unroll
    for (int mi = 0; mi < 4; ++mi)
        #pragma unroll
        for (int ni = 0; ni < 2; ++ni)
            acc[mi][ni] = (f32x4){0.f, 0.f, 0.f, 0.f};

    float4 ra[4], rb[4];
    auto loadAB = [&](int k0) {
        float4 z = make_float4(0.f, 0.f, 0.f, 0.f);
        ra[0] = ra[1] = ra[2] = ra[3] = z;
        int gr = row0 + srow;
        if (gr < GM) {
            const float* s = (gr < GM_ENC)
                ? enc + (size_t)gr * H_ + k0 + scg
                : dec + (size_t)(gr - GM_ENC) * H_ + k0 + scg;
            ra[0] = *(const float4*)s;       ra[1] = *(const float4*)(s + 4);
            ra[2] = *(const float4*)(s + 8); ra[3] = *(const float4*)(s + 12);
        }
        const float* s = W + (size_t)(col0 + srow) * H_ + k0 + scg;
        rb[0] = *(const float4*)s;       rb[1] = *(const float4*)(s + 4);
        rb[2] = *(const float4*)(s + 8); rb[3] = *(const float4*)(s + 12);
    };
    auto stage = [&]() {
        uint4 w0 = { cvt_pk_bf16(ra[0].x, ra[0].y), cvt_pk_bf16(ra[0].z, ra[0].w),
                     cvt_pk_bf16(ra[1].x, ra[1].y), cvt_pk_bf16(ra[1].z, ra[1].w) };
        uint4 w1 = { cvt_pk_bf16(ra[2].x, ra[2].y), cvt_pk_bf16(ra[2].z, ra[2].w),
                     cvt_pk_bf16(ra[3].x, ra[3].y), cvt_pk_bf16(ra[3].z, ra[3].w) };
        uint4 v0 = { cvt_pk_bf16(rb[0].x, rb[0].y), cvt_pk_bf16(rb[0].z, rb[0].w),
                     cvt_pk_bf16(rb[1].x, rb[1].y), cvt_pk_bf16(rb[1].z, rb[1].w) };
        uint4 v1 = { cvt_pk_bf16(rb[2].x, rb[2].y), cvt_pk_bf16(rb[2].z, rb[2].w),
                     cvt_pk_bf16(rb[3].x, rb[3].y), cvt_pk_bf16(rb[3].z, rb[3].w) };
        int colb = scg * 2;
        int sw0 = (colb)      ^ ((srow & 7) << 4);
        int sw1 = (colb + 16) ^ ((srow & 7) << 4);
        *(uint4*)((char*)As + srow * 128 + sw0) = w0;
        *(uint4*)((char*)As + srow * 128 + sw1) = w1;
        *(uint4*)((char*)Bs + srow * 128 + sw0) = v0;
        *(uint4*)((char*)Bs + srow * 128 + sw1) = v1;
    };
    auto compute = [&]() {
        #pragma unroll
        for (int kk = 0; kk < 2; ++kk) {
            short8 a[4], bfr[2];
            const int cb = kk * 64 + (lane >> 4) * 16;
            #pragma unroll
            for (int mi = 0; mi < 4; ++mi) {
                int r = wm * 64 + mi * 16 + (lane & 15);
                a[mi] = *(const short8*)((const char*)As + r * 128 + (cb ^ ((r & 7) << 4)));
            }
            #pragma unroll
            for (int ni = 0; ni < 2; ++ni) {
                int r = wn * 32 + ni * 16 + (lane & 15);
                bfr[ni] = *(const short8*)((const char*)Bs + r * 128 + (cb ^ ((r & 7) << 4)));
            }
            #pragma unroll
            for (int mi = 0; mi < 4; ++mi)
                #pragma unroll
                for (int ni = 0; ni < 2; ++ni)
                    asm("v_mfma_f32_16x16x32_bf16 %0, %1, %2, %0"
                        : "+v"(acc[mi][ni]) : "v"(a[mi]), "v"(bfr[ni]));
        }
    };

    loadAB(0);
    for (int k0 = 0; k0 < H_; k0 += 64) {
        stage();
        asm volatile("s_waitcnt lgkmcnt(0)" ::: "memory");
        __builtin_amdgcn_s_barrier();
        asm volatile("" ::: "memory");
        if (k0 + 64 < H_) loadAB(k0 + 64);
        compute();
        asm volatile("" ::: "memory");
        __builtin_amdgcn_s_barrier();
        asm volatile("" ::: "memory");
    }

    #pragma unroll
    for (int ni = 0; ni < 2; ++ni) {
        int col = col0 + wn * 32 + ni * 16 + (lane & 15);
        float bb = bias[col];
        #pragma unroll
        for (int mi = 0; mi < 4; ++mi) {
            #pragma unroll
            for (int j = 0; j < 4; ++j) {
                int gr = row0 + wm * 64 + mi * 16 + (lane >> 4) * 4 + j;
                if (gr >= GM) continue;
                float v = acc[mi][ni][j] + (gr < GM_ENC ? bb : 0.f);
                Pexp[(size_t)gr * V_ + col] = f2bf(__builtin_amdgcn_exp2f(v * INVLN2));
            }
        }
    }
}

// ---------------- K2: per-batch fused {denom GEMM -> lp in LDS -> DP}.
// 4 blocks x 512 threads. GEMM: M=256(t), N=64(u), K=1024, 8 waves x 32 rows.
// lp arrays live in LDS (fp32, log2-domain), union'd with GEMM staging.
__global__ __launch_bounds__(512) void joint_kernel(
    const unsigned short* __restrict__ Pexp, const int* __restrict__ targets,
    const int* __restrict__ tlen, const int* __restrict__ ulen,
    float* __restrict__ out)
{
    __shared__ __attribute__((aligned(16))) float smem[(2 * U_ + 1) * T_]; // 99328 B
    __shared__ float rowb2[T_];
    __shared__ float colb2[64];
    __shared__ float cu_[64];
    __shared__ int   tgts[64];

    float* pb = smem;                  // [U_+1][T_] log2 P(blank)
    float* pl = smem + (U_ + 1) * T_;  // [U_][T_]   log2 P(label)
    unsigned short* As = (unsigned short*)smem;   // [256][64] bf16 (GEMM phase)
    unsigned short* Bs = As + 256 * 64;           // [64][64]

    const int b    = blockIdx.x;
    const int tid  = threadIdx.x;
    const int lane = tid & 63, wave = tid >> 6;

    // ---- small log2 tables (consumed after >=1 barrier)
    if (tid < T_) {
        rowb2[tid] = __builtin_amdgcn_logf(
            bf2f(Pexp[(size_t)(b * T_ + tid) * V_ + BLANK_]));
    } else if (tid < T_ + 64) {
        int q = tid - T_;
        int uq = q <= U_ ? q : U_;
        size_t drow = (size_t)(GM_ENC + b * (U_ + 1) + uq);
        float cb = __builtin_amdgcn_logf(bf2f(Pexp[drow * V_ + BLANK_]));
        colb2[q] = cb;
        int tg = (q < U_) ? targets[b * U_ + q] : 0;
        tgts[q] = tg;
        size_t drow2 = (size_t)(GM_ENC + b * (U_ + 1) + (q < U_ ? q : U_ - 1));
        cu_[q] = __builtin_amdgcn_logf(bf2f(Pexp[drow2 * V_ + tg])) - cb;
    }

    // ---- GEMM phase
    f32x4 acc[2][4];
    #pragma unroll
    for (int mi = 0; mi < 2; ++mi)
        #pragma unroll
        for (int ni = 0; ni < 4; ++ni)
            acc[mi][ni] = (f32x4){0.f, 0.f, 0.f, 0.f};

    short8 a2[4], b2v;
    auto loadT = [&](int k0) {
        #pragma unroll
        for (int c = 0; c < 4; ++c) {
            int off = (tid + 512 * c) * 16;
            int row = off >> 7, colb = off & 127;
            size_t arow = (size_t)(b * T_ + row);
            a2[c] = *(const short8*)((const char*)Pexp + arow * (V_ * 2) + k0 * 2 + colb);
        }
        {
            int off = tid * 16;
            int row = off >> 7, colb = off & 127;
            size_t brow = (size_t)(GM_ENC + b * (U_ + 1) + (row <= U_ ? row : U_));
            b2v = *(const short8*)((const char*)Pexp + brow * (V_ * 2) + k0 * 2 + colb);
        }
    };
    auto stageT = [&]() {
        #pragma unroll
        for (int c = 0; c < 4; ++c) {
            int off = (tid + 512 * c) * 16;
            int row = off >> 7, colb = off & 127;
            *(short8*)((char*)As + row * 128 + (colb ^ ((row & 7) << 4))) = a2[c];
        }
        {
            int off = tid * 16;
            int row = off >> 7, colb = off & 127;
            *(short8*)((char*)Bs + row * 128 + (colb ^ ((row & 7) << 4))) = b2v;
        }
    };

    loadT(0);
    for (int k0 = 0; k0 < V_; k0 += 64) {
        stageT();
        asm volatile("s_waitcnt lgkmcnt(0)" ::: "memory");
        __builtin_amdgcn_s_barrier();
        asm volatile("" ::: "memory");
        if (k0 + 64 < V_) loadT(k0 + 64);
        #pragma unroll
        for (int kk = 0; kk < 2; ++kk) {
            short8 a[2], bfr[4];
            const int cb = kk * 64 + (lane >> 4) * 16;
            #pragma unroll
            for (int mi = 0; mi < 2; ++mi) {
                int r = wave * 32 + mi * 16 + (lane & 15);
                a[mi] = *(const short8*)((const char*)As + r * 128 + (cb ^ ((r & 7) << 4)));
            }
            #pragma unroll
            for (int ni = 0; ni < 4; ++ni) {
                int r = ni * 16 + (lane & 15);
                bfr[ni] = *(const short8*)((const char*)Bs + r * 128 + (cb ^ ((r & 7) << 4)));
            }
            #pragma unroll
            for (int mi = 0; mi < 2; ++mi)
                #pragma unroll
                for (int ni = 0; ni < 4; ++ni)
                    asm("v_mfma_f32_16x16x32_bf16 %0, %1, %2, %0"
                        : "+v"(acc[mi][ni]) : "v"(a[mi]), "v"(bfr[ni]));
        }
        asm volatile("" ::: "memory");
        __builtin_amdgcn_s_barrier();
        asm volatile("" ::: "memory");
    }
    __syncthreads();   // all GEMM LDS reads done; pb/pl may now overwrite As/Bs

    // ---- epilogue: pb[u][t] = rowb2[t] + colb2[u] - log2(denom)
    #pragma unroll
    for (int ni = 0; ni < 4; ++ni) {
        int u = ni * 16 + (lane & 15);
        if (u <= U_) {
            #pragma unroll
            for (int mi = 0; mi < 2; ++mi) {
                #pragma unroll
                for (int j = 0; j < 4; ++j) {
                    int t = wave * 32 + mi * 16 + (lane >> 4) * 4 + j;
                    float lse2 = __builtin_amdgcn_logf(acc[mi][ni][j]);
                    pb[u * T_ + t] = rowb2[t] + colb2[u] - lse2;
                }
            }
        }
    }
    __syncthreads();

    // ---- pl pass: pl[u][t] = pb[u][t] + (log2 PE[t][tgt_u] - rowb2[t]) + cu[u]
    for (int i = tid; i < U_ * T_; i += 512) {
        int u = i >> 8, t = i & 255;
        float g = __builtin_amdgcn_logf(
            bf2f(Pexp[(size_t)(b * T_ + t) * V_ + tgts[u]]));
        pl[i] = pb[u * T_ + t] + (g - rowb2[t]) + cu_[u];
    }
    __syncthreads();
    if (wave != 0) return;

    // ---- DP phase (wave 0): t-block wavefront, fp32 LDS, DPP boundary
    const int l = lane;
    const int t0 = 4 * l;
    const int TL = tlen[b], UL = ulen[b];
    const int lt = (TL - 1) >> 2;
    const int smax = lt + UL;

    float pu0 = NEGINF, pu1 = NEGINF, pu2 = NEGINF, pu3 = NEGINF;
    float a3 = NEGINF;
    float r0 = 0.f, r1 = 0.f, r2 = 0.f, r3 = 0.f;

    float4 bq, lq; float bx;
    auto issue = [&](int ss, float4& obq, float4& olq, float& obx) {
        int uu = ss - l;
        int ub  = min(max(uu, 0), U_);
        int ul2 = min(max(uu - 1, 0), U_ - 1);
        obq = *(const float4*)(pb + ub * T_ + t0);
        olq = *(const float4*)(pl + ul2 * T_ + t0);
        obx = pb[ub * T_ + (t0 > 0 ? t0 - 1 : 0)];
    };
    issue(0, bq, lq, bx);

    for (int s = 0; s <= smax; ++s) {
        float B0 = bx,   B1 = bq.x, B2 = bq.y, B3 = bq.z;
        float L0 = lq.x, L1 = lq.y, L2 = lq.z, L3 = lq.w;

        float bound = wave_shr1(a3, NEGINF);

        float4 nbq, nlq; float nbx;
        issue(s + 1, nbq, nlq, nbx);

        int u = s - l;
        if (u >= 0 && u <= U_) {
            float y0 = pu0 + L0, y1 = pu1 + L1, y2 = pu2 + L2, y3 = pu3 + L3;
            float a0 = lad2(bound + B0, y0);
            if (l == 0 && u == 0) a0 = 0.f;
            float a1 = lad2(a0 + B1, y1);
            float a2 = lad2(a1 + B2, y2);
            float a3n = lad2(a2 + B3, y3);
            pu0 = a0; pu1 = a1; pu2 = a2; pu3 = a3n;
            a3 = a3n;
            if (u == UL && l == lt) { r0 = a0; r1 = a1; r2 = a2; r3 = a3n; }
        }
        bq = nbq; lq = nlq; bx = nbx;
    }

    if (l == lt) {
        int j = (TL - 1) & 3;
        float a = (j == 0) ? r0 : (j == 1) ? r1 : (j == 2) ? r2 : r3;
        out[b] = -(a + pb[UL * T_ + (TL - 1)]) * LN2F;
    }
}

extern "C" void kernel_launch(void* const* d_in, const int* in_sizes, int n_in,
                              void* d_out, int out_size, void* d_ws, size_t ws_size,
                              hipStream_t stream) {
    const float* enc     = (const float*)d_in[0];
    const float* dec     = (const float*)d_in[1];
    const float* W       = (const float*)d_in[2];
    const float* bias    = (const float*)d_in[3];
    const int*   targets = (const int*)d_in[4];
    const int*   tlen    = (const int*)d_in[5];
    const int*   ulen    = (const int*)d_in[6];
    float* out = (float*)d_out;

    unsigned short* Pexp = (unsigned short*)d_ws;   // APAD x V bf16

    gemm1_kernel<<<dim3(V_/128, APAD/128), dim3(512), 0, stream>>>(
        enc, dec, W, bias, Pexp);

    joint_kernel<<<dim3(B_), dim3(512), 0, stream>>>(
        Pexp, targets, tlen, ulen, out);
}

// Round 8
// 59.451 us; speedup vs baseline: 1.1329x; 1.1329x over previous
//
#include <hip/hip_runtime.h>
#include <math.h>

#define B_ 4
#define T_ 256
#define U_ 48
#define H_ 512
#define V_ 1024
#define BLANK_ (V_-1)

#define GM 1220        // B*T + B*(U+1)
#define GM_ENC 1024    // B*T
#define APAD 1280

#define INVLN2 1.4426950408889634f
#define LN2F   0.6931471805599453f

typedef __attribute__((ext_vector_type(8))) short short8;
typedef __attribute__((ext_vector_type(4))) float f32x4;

__device__ __forceinline__ unsigned short f2bf(float x) {
    union { float f; unsigned int u; } c; c.f = x;
    unsigned int r = c.u + 0x7FFF + ((c.u >> 16) & 1);   // RNE
    return (unsigned short)(r >> 16);
}
__device__ __forceinline__ float bf2f(unsigned short u) {
    union { unsigned int i; float f; } c; c.i = ((unsigned int)u) << 16; return c.f;
}
__device__ __forceinline__ unsigned int cvt_pk_bf16(float lo, float hi) {
    unsigned int r;
    asm("v_cvt_pk_bf16_f32 %0, %1, %2" : "=v"(r) : "v"(lo), "v"(hi));
    return r;
}
// wave-wide shift-right-by-1 via DPP (pure VALU; lane0 <- fill)
__device__ __forceinline__ int wave_shr1_i(int x, int fill) {
    return __builtin_amdgcn_update_dpp(fill, x, 0x138 /*wave_shr:1*/, 0xf, 0xf, false);
}
__device__ __forceinline__ double wave_shr1_d(double x, double fill) {
    unsigned long long xb = __builtin_bit_cast(unsigned long long, x);
    unsigned long long fb = __builtin_bit_cast(unsigned long long, fill);
    int lo = wave_shr1_i((int)(unsigned)xb, (int)(unsigned)fb);
    int hi = wave_shr1_i((int)(xb >> 32), (int)(fb >> 32));
    unsigned long long r = ((unsigned long long)(unsigned)hi << 32) | (unsigned)lo;
    return __builtin_bit_cast(double, r);
}

// ---------------- K1: Pexp = exp(([enc;dec]@W^T + bias)) in bf16 (unchanged from R6/R7)
__global__ __launch_bounds__(512) void gemm1_kernel(
    const float* __restrict__ enc, const float* __restrict__ dec,
    const float* __restrict__ W, const float* __restrict__ bias,
    unsigned short* __restrict__ Pexp)
{
    __shared__ __attribute__((aligned(16))) unsigned short As[128 * 64];
    __shared__ __attribute__((aligned(16))) unsigned short Bs[128 * 64];
    const int tid  = threadIdx.x;
    const int lane = tid & 63, wave = tid >> 6;
    const int wm = wave >> 2, wn = wave & 3;        // 2 x 4 wave grid
    const int row0 = blockIdx.y * 128, col0 = blockIdx.x * 128;
    const int srow = tid >> 2;
    const int scg  = (tid & 3) * 16;

    f32x4 acc[4][2];
    #pragma unroll
    for (int mi = 0; mi < 4; ++mi)
        #pragma unroll
        for (int ni = 0; ni < 2; ++ni)
            acc[mi][ni] = (f32x4){0.f, 0.f, 0.f, 0.f};

    float4 ra[4], rb[4];
    auto loadAB = [&](int k0) {
        float4 z = make_float4(0.f, 0.f, 0.f, 0.f);
        ra[0] = ra[1] = ra[2] = ra[3] = z;
        int gr = row0 + srow;
        if (gr < GM) {
            const float* s = (gr < GM_ENC)
                ? enc + (size_t)gr * H_ + k0 + scg
                : dec + (size_t)(gr - GM_ENC) * H_ + k0 + scg;
            ra[0] = *(const float4*)s;       ra[1] = *(const float4*)(s + 4);
            ra[2] = *(const float4*)(s + 8); ra[3] = *(const float4*)(s + 12);
        }
        const float* s = W + (size_t)(col0 + srow) * H_ + k0 + scg;
        rb[0] = *(const float4*)s;       rb[1] = *(const float4*)(s + 4);
        rb[2] = *(const float4*)(s + 8); rb[3] = *(const float4*)(s + 12);
    };
    auto stage = [&]() {
        uint4 w0 = { cvt_pk_bf16(ra[0].x, ra[0].y), cvt_pk_bf16(ra[0].z, ra[0].w),
                     cvt_pk_bf16(ra[1].x, ra[1].y), cvt_pk_bf16(ra[1].z, ra[1].w) };
        uint4 w1 = { cvt_pk_bf16(ra[2].x, ra[2].y), cvt_pk_bf16(ra[2].z, ra[2].w),
                     cvt_pk_bf16(ra[3].x, ra[3].y), cvt_pk_bf16(ra[3].z, ra[3].w) };
        uint4 v0 = { cvt_pk_bf16(rb[0].x, rb[0].y), cvt_pk_bf16(rb[0].z, rb[0].w),
                     cvt_pk_bf16(rb[1].x, rb[1].y), cvt_pk_bf16(rb[1].z, rb[1].w) };
        uint4 v1 = { cvt_pk_bf16(rb[2].x, rb[2].y), cvt_pk_bf16(rb[2].z, rb[2].w),
                     cvt_pk_bf16(rb[3].x, rb[3].y), cvt_pk_bf16(rb[3].z, rb[3].w) };
        int colb = scg * 2;
        int sw0 = (colb)      ^ ((srow & 7) << 4);
        int sw1 = (colb + 16) ^ ((srow & 7) << 4);
        *(uint4*)((char*)As + srow * 128 + sw0) = w0;
        *(uint4*)((char*)As + srow * 128 + sw1) = w1;
        *(uint4*)((char*)Bs + srow * 128 + sw0) = v0;
        *(uint4*)((char*)Bs + srow * 128 + sw1) = v1;
    };
    auto compute = [&]() {
        #pragma unroll
        for (int kk = 0; kk < 2; ++kk) {
            short8 a[4], bfr[2];
            const int cb = kk * 64 + (lane >> 4) * 16;
            #pragma unroll
            for (int mi = 0; mi < 4; ++mi) {
                int r = wm * 64 + mi * 16 + (lane & 15);
                a[mi] = *(const short8*)((const char*)As + r * 128 + (cb ^ ((r & 7) << 4)));
            }
            #pragma unroll
            for (int ni = 0; ni < 2; ++ni) {
                int r = wn * 32 + ni * 16 + (lane & 15);
                bfr[ni] = *(const short8*)((const char*)Bs + r * 128 + (cb ^ ((r & 7) << 4)));
            }
            #pragma unroll
            for (int mi = 0; mi < 4; ++mi)
                #pragma unroll
                for (int ni = 0; ni < 2; ++ni)
                    asm("v_mfma_f32_16x16x32_bf16 %0, %1, %2, %0"
                        : "+v"(acc[mi][ni]) : "v"(a[mi]), "v"(bfr[ni]));
        }
    };

    loadAB(0);
    for (int k0 = 0; k0 < H_; k0 += 64) {
        stage();
        asm volatile("s_waitcnt lgkmcnt(0)" ::: "memory");
        __builtin_amdgcn_s_barrier();
        asm volatile("" ::: "memory");
        if (k0 + 64 < H_) loadAB(k0 + 64);
        compute();
        asm volatile("" ::: "memory");
        __builtin_amdgcn_s_barrier();
        asm volatile("" ::: "memory");
    }

    #pragma unroll
    for (int ni = 0; ni < 2; ++ni) {
        int col = col0 + wn * 32 + ni * 16 + (lane & 15);
        float bb = bias[col];
        #pragma unroll
        for (int mi = 0; mi < 4; ++mi) {
            #pragma unroll
            for (int j = 0; j < 4; ++j) {
                int gr = row0 + wm * 64 + mi * 16 + (lane >> 4) * 4 + j;
                if (gr >= GM) continue;
                float v = acc[mi][ni][j] + (gr < GM_ENC ? bb : 0.f);
                Pexp[(size_t)gr * V_ + col] = f2bf(__builtin_amdgcn_exp2f(v * INVLN2));
            }
        }
    }
}

// ---------------- K2: denom GEMM + linear fp32 pb/pl epilogue (unchanged from R7)
__global__ __launch_bounds__(256) void gemm2_kernel(
    const unsigned short* __restrict__ Pexp, const int* __restrict__ targets,
    float* __restrict__ lp)
{
    __shared__ __attribute__((aligned(16))) unsigned short As[64 * 64];
    __shared__ __attribute__((aligned(16))) unsigned short Bs[64 * 64];
    __shared__ float eb[64];   // PexpE[t][BLANK]
    __shared__ float db[64];   // PexpD[u][BLANK]
    __shared__ float dg[64];   // PexpD[u][tgt_u]
    __shared__ int   tgts[64];
    const int tid  = threadIdx.x;
    const int lane = tid & 63, wave = tid >> 6;
    const int wm = wave >> 1, wn = wave & 1;
    const int mt = blockIdx.x, b = blockIdx.y;

    if (tid < 64) {
        eb[tid] = bf2f(Pexp[(size_t)(b * 256 + mt * 64 + tid) * V_ + BLANK_]);
    } else if (tid < 128) {
        int u = tid - 64;
        if (u <= U_) {
            size_t drow = (size_t)(GM_ENC + b * (U_ + 1) + u);
            db[u] = bf2f(Pexp[drow * V_ + BLANK_]);
            if (u < U_) {
                int tg = targets[b * U_ + u];
                tgts[u] = tg;
                dg[u] = bf2f(Pexp[drow * V_ + tg]);
            }
        }
    }

    f32x4 acc[2][2];
    #pragma unroll
    for (int mi = 0; mi < 2; ++mi)
        #pragma unroll
        for (int ni = 0; ni < 2; ++ni)
            acc[mi][ni] = (f32x4){0.f, 0.f, 0.f, 0.f};

    short8 a2[2], b2[2];
    auto loadT = [&](int k0) {
        #pragma unroll
        for (int c = 0; c < 2; ++c) {
            int off = (tid + 256 * c) * 16;
            int row = off >> 7, colb = off & 127;
            size_t arow = (size_t)(b * 256 + mt * 64 + row);
            a2[c] = *(const short8*)((const char*)Pexp + arow * (V_*2) + k0*2 + colb);
            size_t brow = (size_t)(GM_ENC + b * (U_ + 1) + (row <= U_ ? row : U_));
            b2[c] = *(const short8*)((const char*)Pexp + brow * (V_*2) + k0*2 + colb);
        }
    };
    auto stageT = [&]() {
        #pragma unroll
        for (int c = 0; c < 2; ++c) {
            int off = (tid + 256 * c) * 16;
            int row = off >> 7, colb = off & 127;
            int sw = colb ^ ((row & 7) << 4);
            *(short8*)((char*)As + row * 128 + sw) = a2[c];
            *(short8*)((char*)Bs + row * 128 + sw) = b2[c];
        }
    };

    loadT(0);
    for (int k0 = 0; k0 < V_; k0 += 64) {
        stageT();
        asm volatile("s_waitcnt lgkmcnt(0)" ::: "memory");
        __builtin_amdgcn_s_barrier();
        asm volatile("" ::: "memory");
        if (k0 + 64 < V_) loadT(k0 + 64);
        #pragma unroll
        for (int kk = 0; kk < 2; ++kk) {
            short8 a[2], bfr[2];
            const int cb = kk * 64 + (lane >> 4) * 16;
            #pragma unroll
            for (int mi = 0; mi < 2; ++mi) {
                int r = wm * 32 + mi * 16 + (lane & 15);
                a[mi] = *(const short8*)((const char*)As + r * 128 + (cb ^ ((r & 7) << 4)));
            }
            #pragma unroll
            for (int ni = 0; ni < 2; ++ni) {
                int r = wn * 32 + ni * 16 + (lane & 15);
                bfr[ni] = *(const short8*)((const char*)Bs + r * 128 + (cb ^ ((r & 7) << 4)));
            }
            #pragma unroll
            for (int mi = 0; mi < 2; ++mi)
                #pragma unroll
                for (int ni = 0; ni < 2; ++ni)
                    asm("v_mfma_f32_16x16x32_bf16 %0, %1, %2, %0"
                        : "+v"(acc[mi][ni]) : "v"(a[mi]), "v"(bfr[ni]));
        }
        asm volatile("" ::: "memory");
        __builtin_amdgcn_s_barrier();
        asm volatile("" ::: "memory");
    }

    // linear epilogue: pb = eb*db/denom ; pl = eg*dg/denom  (both <= 1 by construction:
    // the blank/label product is itself one of the 1024 summands of denom)
    #pragma unroll
    for (int ni = 0; ni < 2; ++ni) {
        int u = wn * 32 + ni * 16 + (lane & 15);
        if (u > U_) continue;
        float dbu = db[u];
        float dgu = (u < U_) ? dg[u] : 0.f;
        int   tgu = (u < U_) ? tgts[u] : 0;
        #pragma unroll
        for (int mi = 0; mi < 2; ++mi) {
            #pragma unroll
            for (int j = 0; j < 4; ++j) {
                int tp = wm * 32 + mi * 16 + (lane >> 4) * 4 + j;
                int t  = mt * 64 + tp;
                float rd = __builtin_amdgcn_rcpf(acc[mi][ni][j]);
                lp[((size_t)b * 97 + u) * T_ + t] = eb[tp] * dbu * rd;
                if (u < U_) {
                    float eg = bf2f(Pexp[(size_t)(b * 256 + t) * V_ + tgu]);
                    lp[((size_t)b * 97 + 49 + u) * T_ + t] = eg * dgu * rd;
                }
            }
        }
    }
}

// ---------------- K3: RNN-T alpha DP, scaled LINEAR domain in fp64.
// Lane l owns t in [4l,4l+3]; superstep s: u = s-l. 4 f64 FMAs per superstep on the
// chain; per-lane (M,E) scaling, renorm every 8 supersteps (f64 headroom >> drift).
__global__ __launch_bounds__(256) void dp_kernel(
    const float* __restrict__ lp,
    const int* __restrict__ tlen, const int* __restrict__ ulen,
    float* __restrict__ out)
{
    __shared__ __attribute__((aligned(16))) float sm[97 * T_];  // pb[49][256] | pl[48][256]
    float* pb = sm;
    float* pl = sm + 49 * T_;
    const int b = blockIdx.x;
    const int tid = threadIdx.x;
    {
        const float4* g = (const float4*)(lp + (size_t)b * 97 * T_);
        float4* s4 = (float4*)sm;
        for (int i = tid; i < 97 * T_ / 4; i += 256) s4[i] = g[i];
    }
    __syncthreads();
    if (tid >= 64) return;

    const int l = tid;
    const int t0 = 4 * l;
    const int TL = tlen[b], UL = ulen[b];
    const int lt = (TL - 1) >> 2;
    const int smax = lt + UL;

    double M0 = 0.0, M1 = 0.0, M2 = 0.0, M3 = 0.0;  // alpha[t0+j][u] * 2^-E
    int E = 0;
    double resm = 1.0; int resE = 0;

    struct Pay { float4 bq, lq; float bx; };
    auto issue = [&](int ss, Pay& P) {
        int uu = ss - l;
        int ub = min(max(uu, 0), U_);
        int ul = min(max(uu - 1, 0), U_ - 1);
        P.bq = *(const float4*)(pb + ub * T_ + t0);
        P.lq = *(const float4*)(pl + ul * T_ + t0);
        P.bx = pb[ub * T_ + (t0 > 0 ? t0 - 1 : 0)];
    };
    auto step = [&](int s, Pay& P) {
        // neighbor boundary (alpha[t0-1][u]) from lane l-1's state: pure-VALU DPP
        double bm = wave_shr1_d(M3, 0.0);
        int    bE = wave_shr1_i(E, 0);
        int u = s - l;
        if (u >= 0 && u <= U_) {
            int Eu = (u == 0) ? bE : E;          // adopt neighbor scale at activation
            double sb = ldexp(bm, bE - Eu);
            double q0 = M0 * (double)P.lq.x, q1 = M1 * (double)P.lq.y;
            double q2 = M2 * (double)P.lq.z, q3 = M3 * (double)P.lq.w;
            double A0 = fma(sb, (double)P.bx, q0);
            if (l == 0 && u == 0) A0 = 1.0;      // alpha[0][0] = 1
            double A1 = fma(A0, (double)P.bq.x, q1);
            double A2 = fma(A1, (double)P.bq.y, q2);
            double A3 = fma(A2, (double)P.bq.z, q3);
            if (u == UL && l == lt) {
                int j = (TL - 1) & 3;
                resm = (j == 0) ? A0 : (j == 1) ? A1 : (j == 2) ? A2 : A3;
                resE = Eu;
            }
            M0 = A0; M1 = A1; M2 = A2; M3 = A3; E = Eu;
            if ((s & 7) == 7) {                  // renorm (active lanes only: A3 > 0 normal)
                unsigned long long bits = __builtin_bit_cast(unsigned long long, A3);
                int e3 = (int)((bits >> 52) & 0x7FF) - 1022;
                M3 = __builtin_bit_cast(double,
                        (bits & 0x800FFFFFFFFFFFFFULL) | 0x3FE0000000000000ULL);
                M0 = ldexp(A0, -e3);
                M1 = ldexp(A1, -e3);
                M2 = ldexp(A2, -e3);
                E += e3;
            }
        }
    };

    Pay pA, pB;
    issue(0, pA); issue(1, pB);
    int s = 0;
    for (; s + 1 <= smax; s += 2) {
        step(s, pA);     issue(s + 2, pA);
        step(s + 1, pB); issue(s + 3, pB);
    }
    if (s <= smax) step(s, pA);

    if (l == lt) {
        unsigned long long rb = __builtin_bit_cast(unsigned long long, resm);
        int re = (int)((rb >> 52) & 0x7FF) - 1022;
        double rm = __builtin_bit_cast(double,
                      (rb & 0x800FFFFFFFFFFFFFULL) | 0x3FE0000000000000ULL);
        float lfin = __builtin_amdgcn_logf((float)rm) + (float)(re + resE)
                   + __builtin_amdgcn_logf(pb[UL * T_ + (TL - 1)]);
        out[b] = -lfin * LN2F;
    }
}

extern "C" void kernel_launch(void* const* d_in, const int* in_sizes, int n_in,
                              void* d_out, int out_size, void* d_ws, size_t ws_size,
                              hipStream_t stream) {
    const float* enc     = (const float*)d_in[0];
    const float* dec     = (const float*)d_in[1];
    const float* W       = (const float*)d_in[2];
    const float* bias    = (const float*)d_in[3];
    const int*   targets = (const int*)d_in[4];
    const int*   tlen    = (const int*)d_in[5];
    const int*   ulen    = (const int*)d_in[6];
    float* out = (float*)d_out;

    unsigned short* Pexp = (unsigned short*)d_ws;       // APAD x V bf16 (e^logit factors)
    float* lp = (float*)(Pexp + (size_t)APAD * V_);     // [B][97][T] linear fp32 probs

    gemm1_kernel<<<dim3(V_/128, APAD/128), dim3(512), 0, stream>>>(
        enc, dec, W, bias, Pexp);

    gemm2_kernel<<<dim3(4, B_), dim3(256), 0, stream>>>(Pexp, targets, lp);

    dp_kernel<<<dim3(B_), dim3(256), 0, stream>>>(lp, tlen, ulen, out);
}

// Round 9
// 57.038 us; speedup vs baseline: 1.1808x; 1.0423x over previous
//
#include <hip/hip_runtime.h>
#include <math.h>

#define B_ 4
#define T_ 256
#define U_ 48
#define H_ 512
#define V_ 1024
#define BLANK_ (V_-1)

#define GM 1220        // B*T + B*(U+1)
#define GM_ENC 1024    // B*T
#define APAD 1280

#define INVLN2 1.4426950408889634f
#define LN2F   0.6931471805599453f

typedef __attribute__((ext_vector_type(8))) short short8;
typedef __attribute__((ext_vector_type(4))) float f32x4;

__device__ __forceinline__ unsigned short f2bf(float x) {
    union { float f; unsigned int u; } c; c.f = x;
    unsigned int r = c.u + 0x7FFF + ((c.u >> 16) & 1);   // RNE
    return (unsigned short)(r >> 16);
}
__device__ __forceinline__ float bf2f(unsigned short u) {
    union { unsigned int i; float f; } c; c.i = ((unsigned int)u) << 16; return c.f;
}
__device__ __forceinline__ unsigned int cvt_pk_bf16(float lo, float hi) {
    unsigned int r;
    asm("v_cvt_pk_bf16_f32 %0, %1, %2" : "=v"(r) : "v"(lo), "v"(hi));
    return r;
}
// wave-wide shift-right-by-1 via DPP (pure VALU; lane0 <- fill)
__device__ __forceinline__ int wave_shr1_i(int x, int fill) {
    return __builtin_amdgcn_update_dpp(fill, x, 0x138 /*wave_shr:1*/, 0xf, 0xf, false);
}
__device__ __forceinline__ float wave_shr1_f(float x, float fill) {
    return __builtin_bit_cast(float,
        wave_shr1_i(__builtin_bit_cast(int, x), __builtin_bit_cast(int, fill)));
}
__device__ __forceinline__ double wave_shr1_d(double x, double fill) {
    unsigned long long xb = __builtin_bit_cast(unsigned long long, x);
    unsigned long long fb = __builtin_bit_cast(unsigned long long, fill);
    int lo = wave_shr1_i((int)(unsigned)xb, (int)(unsigned)fb);
    int hi = wave_shr1_i((int)(xb >> 32), (int)(fb >> 32));
    unsigned long long r = ((unsigned long long)(unsigned)hi << 32) | (unsigned)lo;
    return __builtin_bit_cast(double, r);
}

// ---------------- K1: Pexp = exp(([enc;dec]@W^T + bias)) in bf16 (unchanged from R8)
__global__ __launch_bounds__(512) void gemm1_kernel(
    const float* __restrict__ enc, const float* __restrict__ dec,
    const float* __restrict__ W, const float* __restrict__ bias,
    unsigned short* __restrict__ Pexp)
{
    __shared__ __attribute__((aligned(16))) unsigned short As[128 * 64];
    __shared__ __attribute__((aligned(16))) unsigned short Bs[128 * 64];
    const int tid  = threadIdx.x;
    const int lane = tid & 63, wave = tid >> 6;
    const int wm = wave >> 2, wn = wave & 3;        // 2 x 4 wave grid
    const int row0 = blockIdx.y * 128, col0 = blockIdx.x * 128;
    const int srow = tid >> 2;
    const int scg  = (tid & 3) * 16;

    f32x4 acc[4][2];
    #pragma unroll
    for (int mi = 0; mi < 4; ++mi)
        #pragma unroll
        for (int ni = 0; ni < 2; ++ni)
            acc[mi][ni] = (f32x4){0.f, 0.f, 0.f, 0.f};

    float4 ra[4], rb[4];
    auto loadAB = [&](int k0) {
        float4 z = make_float4(0.f, 0.f, 0.f, 0.f);
        ra[0] = ra[1] = ra[2] = ra[3] = z;
        int gr = row0 + srow;
        if (gr < GM) {
            const float* s = (gr < GM_ENC)
                ? enc + (size_t)gr * H_ + k0 + scg
                : dec + (size_t)(gr - GM_ENC) * H_ + k0 + scg;
            ra[0] = *(const float4*)s;       ra[1] = *(const float4*)(s + 4);
            ra[2] = *(const float4*)(s + 8); ra[3] = *(const float4*)(s + 12);
        }
        const float* s = W + (size_t)(col0 + srow) * H_ + k0 + scg;
        rb[0] = *(const float4*)s;       rb[1] = *(const float4*)(s + 4);
        rb[2] = *(const float4*)(s + 8); rb[3] = *(const float4*)(s + 12);
    };
    auto stage = [&]() {
        uint4 w0 = { cvt_pk_bf16(ra[0].x, ra[0].y), cvt_pk_bf16(ra[0].z, ra[0].w),
                     cvt_pk_bf16(ra[1].x, ra[1].y), cvt_pk_bf16(ra[1].z, ra[1].w) };
        uint4 w1 = { cvt_pk_bf16(ra[2].x, ra[2].y), cvt_pk_bf16(ra[2].z, ra[2].w),
                     cvt_pk_bf16(ra[3].x, ra[3].y), cvt_pk_bf16(ra[3].z, ra[3].w) };
        uint4 v0 = { cvt_pk_bf16(rb[0].x, rb[0].y), cvt_pk_bf16(rb[0].z, rb[0].w),
                     cvt_pk_bf16(rb[1].x, rb[1].y), cvt_pk_bf16(rb[1].z, rb[1].w) };
        uint4 v1 = { cvt_pk_bf16(rb[2].x, rb[2].y), cvt_pk_bf16(rb[2].z, rb[2].w),
                     cvt_pk_bf16(rb[3].x, rb[3].y), cvt_pk_bf16(rb[3].z, rb[3].w) };
        int colb = scg * 2;
        int sw0 = (colb)      ^ ((srow & 7) << 4);
        int sw1 = (colb + 16) ^ ((srow & 7) << 4);
        *(uint4*)((char*)As + srow * 128 + sw0) = w0;
        *(uint4*)((char*)As + srow * 128 + sw1) = w1;
        *(uint4*)((char*)Bs + srow * 128 + sw0) = v0;
        *(uint4*)((char*)Bs + srow * 128 + sw1) = v1;
    };
    auto compute = [&]() {
        #pragma unroll
        for (int kk = 0; kk < 2; ++kk) {
            short8 a[4], bfr[2];
            const int cb = kk * 64 + (lane >> 4) * 16;
            #pragma unroll
            for (int mi = 0; mi < 4; ++mi) {
                int r = wm * 64 + mi * 16 + (lane & 15);
                a[mi] = *(const short8*)((const char*)As + r * 128 + (cb ^ ((r & 7) << 4)));
            }
            #pragma unroll
            for (int ni = 0; ni < 2; ++ni) {
                int r = wn * 32 + ni * 16 + (lane & 15);
                bfr[ni] = *(const short8*)((const char*)Bs + r * 128 + (cb ^ ((r & 7) << 4)));
            }
            #pragma unroll
            for (int mi = 0; mi < 4; ++mi)
                #pragma unroll
                for (int ni = 0; ni < 2; ++ni)
                    asm("v_mfma_f32_16x16x32_bf16 %0, %1, %2, %0"
                        : "+v"(acc[mi][ni]) : "v"(a[mi]), "v"(bfr[ni]));
        }
    };

    loadAB(0);
    for (int k0 = 0; k0 < H_; k0 += 64) {
        stage();
        asm volatile("s_waitcnt lgkmcnt(0)" ::: "memory");
        __builtin_amdgcn_s_barrier();
        asm volatile("" ::: "memory");
        if (k0 + 64 < H_) loadAB(k0 + 64);
        compute();
        asm volatile("" ::: "memory");
        __builtin_amdgcn_s_barrier();
        asm volatile("" ::: "memory");
    }

    #pragma unroll
    for (int ni = 0; ni < 2; ++ni) {
        int col = col0 + wn * 32 + ni * 16 + (lane & 15);
        float bb = bias[col];
        #pragma unroll
        for (int mi = 0; mi < 4; ++mi) {
            #pragma unroll
            for (int j = 0; j < 4; ++j) {
                int gr = row0 + wm * 64 + mi * 16 + (lane >> 4) * 4 + j;
                if (gr >= GM) continue;
                float v = acc[mi][ni][j] + (gr < GM_ENC ? bb : 0.f);
                Pexp[(size_t)gr * V_ + col] = f2bf(__builtin_amdgcn_exp2f(v * INVLN2));
            }
        }
    }
}

// ---------------- K2: denom GEMM + linear fp32 pb/pl epilogue (unchanged from R8)
__global__ __launch_bounds__(256) void gemm2_kernel(
    const unsigned short* __restrict__ Pexp, const int* __restrict__ targets,
    float* __restrict__ lp)
{
    __shared__ __attribute__((aligned(16))) unsigned short As[64 * 64];
    __shared__ __attribute__((aligned(16))) unsigned short Bs[64 * 64];
    __shared__ float eb[64];   // PexpE[t][BLANK]
    __shared__ float db[64];   // PexpD[u][BLANK]
    __shared__ float dg[64];   // PexpD[u][tgt_u]
    __shared__ int   tgts[64];
    const int tid  = threadIdx.x;
    const int lane = tid & 63, wave = tid >> 6;
    const int wm = wave >> 1, wn = wave & 1;
    const int mt = blockIdx.x, b = blockIdx.y;

    if (tid < 64) {
        eb[tid] = bf2f(Pexp[(size_t)(b * 256 + mt * 64 + tid) * V_ + BLANK_]);
    } else if (tid < 128) {
        int u = tid - 64;
        if (u <= U_) {
            size_t drow = (size_t)(GM_ENC + b * (U_ + 1) + u);
            db[u] = bf2f(Pexp[drow * V_ + BLANK_]);
            if (u < U_) {
                int tg = targets[b * U_ + u];
                tgts[u] = tg;
                dg[u] = bf2f(Pexp[drow * V_ + tg]);
            }
        }
    }

    f32x4 acc[2][2];
    #pragma unroll
    for (int mi = 0; mi < 2; ++mi)
        #pragma unroll
        for (int ni = 0; ni < 2; ++ni)
            acc[mi][ni] = (f32x4){0.f, 0.f, 0.f, 0.f};

    short8 a2[2], b2[2];
    auto loadT = [&](int k0) {
        #pragma unroll
        for (int c = 0; c < 2; ++c) {
            int off = (tid + 256 * c) * 16;
            int row = off >> 7, colb = off & 127;
            size_t arow = (size_t)(b * 256 + mt * 64 + row);
            a2[c] = *(const short8*)((const char*)Pexp + arow * (V_*2) + k0*2 + colb);
            size_t brow = (size_t)(GM_ENC + b * (U_ + 1) + (row <= U_ ? row : U_));
            b2[c] = *(const short8*)((const char*)Pexp + brow * (V_*2) + k0*2 + colb);
        }
    };
    auto stageT = [&]() {
        #pragma unroll
        for (int c = 0; c < 2; ++c) {
            int off = (tid + 256 * c) * 16;
            int row = off >> 7, colb = off & 127;
            int sw = colb ^ ((row & 7) << 4);
            *(short8*)((char*)As + row * 128 + sw) = a2[c];
            *(short8*)((char*)Bs + row * 128 + sw) = b2[c];
        }
    };

    loadT(0);
    for (int k0 = 0; k0 < V_; k0 += 64) {
        stageT();
        asm volatile("s_waitcnt lgkmcnt(0)" ::: "memory");
        __builtin_amdgcn_s_barrier();
        asm volatile("" ::: "memory");
        if (k0 + 64 < V_) loadT(k0 + 64);
        #pragma unroll
        for (int kk = 0; kk < 2; ++kk) {
            short8 a[2], bfr[2];
            const int cb = kk * 64 + (lane >> 4) * 16;
            #pragma unroll
            for (int mi = 0; mi < 2; ++mi) {
                int r = wm * 32 + mi * 16 + (lane & 15);
                a[mi] = *(const short8*)((const char*)As + r * 128 + (cb ^ ((r & 7) << 4)));
            }
            #pragma unroll
            for (int ni = 0; ni < 2; ++ni) {
                int r = wn * 32 + ni * 16 + (lane & 15);
                bfr[ni] = *(const short8*)((const char*)Bs + r * 128 + (cb ^ ((r & 7) << 4)));
            }
            #pragma unroll
            for (int mi = 0; mi < 2; ++mi)
                #pragma unroll
                for (int ni = 0; ni < 2; ++ni)
                    asm("v_mfma_f32_16x16x32_bf16 %0, %1, %2, %0"
                        : "+v"(acc[mi][ni]) : "v"(a[mi]), "v"(bfr[ni]));
        }
        asm volatile("" ::: "memory");
        __builtin_amdgcn_s_barrier();
        asm volatile("" ::: "memory");
    }

    // linear epilogue: pb = eb*db/denom ; pl = eg*dg/denom
    #pragma unroll
    for (int ni = 0; ni < 2; ++ni) {
        int u = wn * 32 + ni * 16 + (lane & 15);
        if (u > U_) continue;
        float dbu = db[u];
        float dgu = (u < U_) ? dg[u] : 0.f;
        int   tgu = (u < U_) ? tgts[u] : 0;
        #pragma unroll
        for (int mi = 0; mi < 2; ++mi) {
            #pragma unroll
            for (int j = 0; j < 4; ++j) {
                int tp = wm * 32 + mi * 16 + (lane >> 4) * 4 + j;
                int t  = mt * 64 + tp;
                float rd = __builtin_amdgcn_rcpf(acc[mi][ni][j]);
                lp[((size_t)b * 97 + u) * T_ + t] = eb[tp] * dbu * rd;
                if (u < U_) {
                    float eg = bf2f(Pexp[(size_t)(b * 256 + t) * V_ + tgu]);
                    lp[((size_t)b * 97 + 49 + u) * T_ + t] = eg * dgu * rd;
                }
            }
        }
    }
}

// ---------------- K3: RNN-T alpha DP, scaled linear f64 — SLIM superstep.
// Lane l owns t in [4l,4l+3]; superstep s: u = s-l. Incremental clamped LDS
// addressing; pb[u][t0-1] via DPP of prev-superstep bq.w; result read after loop.
__global__ __launch_bounds__(256) void dp_kernel(
    const float* __restrict__ lp,
    const int* __restrict__ tlen, const int* __restrict__ ulen,
    float* __restrict__ out)
{
    __shared__ __attribute__((aligned(16))) float sm[97 * T_];  // pb[49][256] | pl[48][256]
    const int b = blockIdx.x;
    const int tid = threadIdx.x;
    {
        const float4* g = (const float4*)(lp + (size_t)b * 97 * T_);
        float4* s4 = (float4*)sm;
        for (int i = tid; i < 97 * T_ / 4; i += 256) s4[i] = g[i];
    }
    __syncthreads();
    if (tid >= 64) return;

    const int l = tid;
    const int t0 = 4 * l;
    const int TL = tlen[b], UL = ulen[b];
    const int lt = (TL - 1) >> 2;
    const int smax = lt + UL;

    // byte offsets: pb row u at u*1024 + t0*4 ; pl row ul at 49*1024 + ul*1024 + t0*4
    const int bLo = t0 * 4, bHi = t0 * 4 + U_ * 1024;            // clamp u to [0,48]
    const int lLo = 49 * 1024 + t0 * 4;                          // clamp ul to [0,47]
    const int lHi = 49 * 1024 + (U_ - 1) * 1024 + t0 * 4;
    int wb = -l * 1024 + t0 * 4;                                 // uu*1024 + t0*4

    double M0 = 0.0, M1 = 0.0, M2 = 0.0, M3 = 0.0;
    int E = 0;
    float wprev = 0.f;                                           // prev superstep's bq.w

    float4 bqA, lqA, bqB, lqB;
    auto issue = [&](float4& bq, float4& lq) {
        int ab = min(max(wb, bLo), bHi);
        int al = min(max(wb + 48 * 1024, lLo), lHi);             // (uu-1)*1024 + plbase
        bq = *(const float4*)((const char*)sm + ab);
        lq = *(const float4*)((const char*)sm + al);
        wb += 1024;
    };
    auto step = [&](int s, const float4& bq, const float4& lq) {
        double bm = wave_shr1_d(M3, 0.0);
        int    bE = wave_shr1_i(E, 0);
        float B0f = wave_shr1_f(wprev, 0.f);
        wprev = bq.w;
        int u = s - l;
        if (u >= 0 && u <= U_) {
            int Eu = (u == 0) ? bE : E;
            double sb = ldexp(bm, bE - Eu);
            double q0 = M0 * (double)lq.x, q1 = M1 * (double)lq.y;
            double q2 = M2 * (double)lq.z, q3 = M3 * (double)lq.w;
            double A0 = fma(sb, (double)B0f, q0);
            if (s == 0 && l == 0) A0 = 1.0;                      // alpha[0][0] = 1
            double A1 = fma(A0, (double)bq.x, q1);
            double A2 = fma(A1, (double)bq.y, q2);
            double A3 = fma(A2, (double)bq.z, q3);
            M0 = A0; M1 = A1; M2 = A2; M3 = A3; E = Eu;
            if ((s & 7) == 7 && A3 > 0.0) {
                unsigned long long bits = __builtin_bit_cast(unsigned long long, A3);
                int e3 = (int)((bits >> 52) & 0x7FF) - 1022;
                M3 = __builtin_bit_cast(double,
                        (bits & 0x800FFFFFFFFFFFFFULL) | 0x3FE0000000000000ULL);
                M0 = ldexp(A0, -e3);
                M1 = ldexp(A1, -e3);
                M2 = ldexp(A2, -e3);
                E += e3;
            }
        }
    };

    issue(bqA, lqA);
    issue(bqB, lqB);
    int s = 0;
    for (; s + 1 <= smax; s += 2) {
        step(s, bqA, lqA);     issue(bqA, lqA);
        step(s + 1, bqB, lqB); issue(bqB, lqB);
    }
    if (s <= smax) step(s, bqA, lqA);

    if (l == lt) {
        int j = (TL - 1) & 3;
        double rm = (j == 0) ? M0 : (j == 1) ? M1 : (j == 2) ? M2 : M3;
        unsigned long long rb = __builtin_bit_cast(unsigned long long, rm);
        int re = (int)((rb >> 52) & 0x7FF) - 1022;
        double rmn = __builtin_bit_cast(double,
                       (rb & 0x800FFFFFFFFFFFFFULL) | 0x3FE0000000000000ULL);
        float lfin = __builtin_amdgcn_logf((float)rmn) + (float)(re + E)
                   + __builtin_amdgcn_logf(sm[UL * T_ + (TL - 1)]);
        out[b] = -lfin * LN2F;
    }
}

extern "C" void kernel_launch(void* const* d_in, const int* in_sizes, int n_in,
                              void* d_out, int out_size, void* d_ws, size_t ws_size,
                              hipStream_t stream) {
    const float* enc     = (const float*)d_in[0];
    const float* dec     = (const float*)d_in[1];
    const float* W       = (const float*)d_in[2];
    const float* bias    = (const float*)d_in[3];
    const int*   targets = (const int*)d_in[4];
    const int*   tlen    = (const int*)d_in[5];
    const int*   ulen    = (const int*)d_in[6];
    float* out = (float*)d_out;

    unsigned short* Pexp = (unsigned short*)d_ws;       // APAD x V bf16 (e^logit factors)
    float* lp = (float*)(Pexp + (size_t)APAD * V_);     // [B][97][T] linear fp32 probs

    gemm1_kernel<<<dim3(V_/128, APAD/128), dim3(512), 0, stream>>>(
        enc, dec, W, bias, Pexp);

    gemm2_kernel<<<dim3(4, B_), dim3(256), 0, stream>>>(Pexp, targets, lp);

    dp_kernel<<<dim3(B_), dim3(256), 0, stream>>>(lp, tlen, ulen, out);
}